// Round 5
// baseline (260.424 us; speedup 1.0000x reference)
//
#include <hip/hip_runtime.h>
#include <stdint.h>

#define T_TOK 4096
#define E_DIM 1024
#define H_N   16
#define D_HD  64
#define NSEG  8

typedef unsigned short u16;
typedef uint32_t       u32;
typedef __bf16          bf16x8 __attribute__((ext_vector_type(8)));
typedef float           f32x4  __attribute__((ext_vector_type(4)));
typedef unsigned short  us8    __attribute__((ext_vector_type(8)));
typedef unsigned short  us4    __attribute__((ext_vector_type(4)));
typedef uint32_t        u32x4  __attribute__((ext_vector_type(4)));

__device__ __forceinline__ u16 f2bf(float f) {
  uint32_t u = __builtin_bit_cast(uint32_t, f);
  u += 0x7FFFu + ((u >> 16) & 1u);
  return (u16)(u >> 16);
}

__device__ __forceinline__ f32x4 mfma16(us8 a, us8 b, f32x4 c) {
  return __builtin_amdgcn_mfma_f32_16x16x32_bf16(
      __builtin_bit_cast(bf16x8, a), __builtin_bit_cast(bf16x8, b), c, 0, 0, 0);
}

__device__ __forceinline__ void async_load16(const void* g, void* l) {
  __builtin_amdgcn_global_load_lds(
      (const __attribute__((address_space(1))) void*)g,
      (__attribute__((address_space(3))) void*)l, 16, 0, 0);
}

// ---------------- fp32 -> bf16 conversion (hidden, Wqkv fused, Wo) ----------
__global__ __launch_bounds__(256) void cvt_all(
    const float* __restrict__ hs, const float* __restrict__ wq,
    const float* __restrict__ wk, const float* __restrict__ wv,
    const float* __restrict__ wo,
    u16* __restrict__ xb, u16* __restrict__ wqkv, u16* __restrict__ wob) {
  const int NH = T_TOK * E_DIM / 4;   // 1048576 float4s
  const int NW = E_DIM * E_DIM / 4;   // 262144 float4s
  int i = blockIdx.x * 256 + threadIdx.x;
  const float4* src; u16* dst; size_t off;
  if (i < NH)            { src = (const float4*)hs; dst = xb;   off = i; }
  else if (i < NH+NW)    { src = (const float4*)wq; dst = wqkv; off = i - NH;          src += off; off += 0;      goto L; }
  else if (i < NH+2*NW)  { src = (const float4*)wk; dst = wqkv; off = i - NH - NW;     src += off; off += NW;     goto L; }
  else if (i < NH+3*NW)  { src = (const float4*)wv; dst = wqkv; off = i - NH - 2*NW;   src += off; off += 2*NW;   goto L; }
  else                   { src = (const float4*)wo; dst = wob;  off = i - NH - 3*NW;   src += off;                goto L; }
  src += off;
L:
  float4 v = *src;
  us4 o;
  o[0] = f2bf(v.x); o[1] = f2bf(v.y); o[2] = f2bf(v.z); o[3] = f2bf(v.w);
  *(us4*)(dst + off * 4) = o;
}

// ---------------- bf16 GEMM: C[M,N] = A[M,K] * B[N,K]^T + bias --------------
// MODE 0: N=3072 -> Q,K in [H][T][D] bf16; V transposed [H*D][T] bf16
// MODE 1: fp32 out + bias0
template <int MODE>
__global__ __launch_bounds__(256, 2) void gemm_bt(
    const u16* __restrict__ A, const u16* __restrict__ B,
    int M, int N, int K,
    const float* __restrict__ bias0, const float* __restrict__ bias1,
    const float* __restrict__ bias2,
    u16* __restrict__ out_q, u16* __restrict__ out_k, u16* __restrict__ out_v,
    float* __restrict__ out_f) {
  __shared__ u16 As[2][128 * 32];
  __shared__ u16 Bs[2][128 * 32];

  const int nbn = N / 128;
  int bm = blockIdx.x / nbn, bn = blockIdx.x % nbn;
  int m0 = bm * 128, n0 = bn * 128;
  int tid = threadIdx.x, lane = tid & 63, wave = tid >> 6;
  int wr = wave >> 1, wc = wave & 1;

  f32x4 acc[4][4] = {};

  auto stage = [&](int bufi, int k0) {
#pragma unroll
    for (int r = 0; r < 2; ++r) {
      int chunk = r * 4 + wave;                 // 1KB chunk, wave-uniform
      int elem = chunk * 512 + lane * 8;        // elems into 128x32 tile
      int row = elem >> 5, kc = elem & 31;
      async_load16(A + (size_t)(m0 + row) * K + k0 + kc, (char*)As[bufi] + chunk * 1024);
      async_load16(B + (size_t)(n0 + row) * K + k0 + kc, (char*)Bs[bufi] + chunk * 1024);
    }
  };

  stage(0, 0);
  __syncthreads();
  int NT = K / 32;
  int lrow = lane & 15, lk = (lane >> 4) * 8;
  for (int t = 0; t < NT; ++t) {
    int buf = t & 1;
    if (t + 1 < NT) stage(buf ^ 1, (t + 1) * 32);
    us8 a[4], b[4];
#pragma unroll
    for (int i = 0; i < 4; ++i) {
      a[i] = *(const us8*)&As[buf][(wr * 64 + i * 16 + lrow) * 32 + lk];
      b[i] = *(const us8*)&Bs[buf][(wc * 64 + i * 16 + lrow) * 32 + lk];
    }
#pragma unroll
    for (int i = 0; i < 4; ++i)
#pragma unroll
      for (int j = 0; j < 4; ++j)
        acc[i][j] = mfma16(a[i], b[j], acc[i][j]);
    __syncthreads();
  }

  int lg = lane >> 4;
#pragma unroll
  for (int i = 0; i < 4; ++i) {
#pragma unroll
    for (int j = 0; j < 4; ++j) {
      int col = n0 + wc * 64 + j * 16 + lrow;
      int row0 = m0 + wr * 64 + i * 16 + lg * 4;
      if (MODE == 0) {
        if (col < 1024) {
          int hh = col >> 6, dd = col & 63;
          float bb = bias0[col];
          u16* dst = out_q + (size_t)hh * (T_TOK * D_HD) + dd;
#pragma unroll
          for (int r = 0; r < 4; ++r)
            dst[(size_t)(row0 + r) * D_HD] = f2bf(acc[i][j][r] + bb);
        } else if (col < 2048) {
          int c = col - 1024;
          int hh = c >> 6, dd = c & 63;
          float bb = bias1[c];
          u16* dst = out_k + (size_t)hh * (T_TOK * D_HD) + dd;
#pragma unroll
          for (int r = 0; r < 4; ++r)
            dst[(size_t)(row0 + r) * D_HD] = f2bf(acc[i][j][r] + bb);
        } else {
          int vc = col - 2048;                 // = h*64 + d
          float bb = bias2[vc];
          us4 o;
#pragma unroll
          for (int r = 0; r < 4; ++r) o[r] = f2bf(acc[i][j][r] + bb);
          *(us4*)&out_v[(size_t)vc * T_TOK + row0] = o;
        }
      } else {
        float bb = bias0[col];
#pragma unroll
        for (int r = 0; r < 4; ++r)
          out_f[(size_t)(row0 + r) * 1024 + col] = acc[i][j][r] + bb;
      }
    }
  }
}

// ---------------- varlen flash attention, swapped-layout, LDS-free ----------
// grid (T/64, H); block 256 = 4 independent waves, wave = 16 q-rows
// Key-to-fragment permutation: frag f, C-row i=lg*4+r  <->  key_local =
//   (f&1)*32 + lg*8 + (f>>1)*4 + r
// chosen so each lane's 16 P-values are exactly its PV B-fragment keys.
__global__ __launch_bounds__(256, 4) void attn_varlen2(
    const u16* __restrict__ Qh, const u16* __restrict__ Kh,
    const u16* __restrict__ Vt, const int* __restrict__ cu,
    u16* __restrict__ Ctx) {
  int h = blockIdx.y;
  int tid = threadIdx.x, lane = tid & 63, wave = tid >> 6;
  int lrow = lane & 15, lg = lane >> 4;
  int q0w = blockIdx.x * 64 + wave * 16;
  int q = q0w + lrow;

  int cuv[NSEG + 1];
#pragma unroll
  for (int i = 0; i <= NSEG; ++i) cuv[i] = cu[i];

  int s = 0, sl = 0, sh = 0;
#pragma unroll
  for (int i = 1; i < NSEG; ++i) {
    s  += (q >= cuv[i]);
    sl += (q0w >= cuv[i]);
    sh += (q0w + 15 >= cuv[i]);
  }
  int kb = cuv[s], ke = cuv[s + 1];          // this lane's q segment
  int kstart = cuv[sl], kend = cuv[sh + 1];  // wave's union range

  const u16* qp = Qh + ((size_t)h * T_TOK + q) * D_HD + lg * 8;
  us8 qB0 = *(const us8*)(qp);
  us8 qB1 = *(const us8*)(qp + 32);

  const u16* Kbase = Kh + (size_t)h * (T_TOK * D_HD);
  const u16* Vbase = Vt + (size_t)h * (D_HD * T_TOK) + (size_t)lrow * T_TOK;

  const float scale2 = 0.125f * 1.44269504f;  // scale * log2(e)
  float mrun = -1e30f, lrun = 0.f;
  f32x4 accO[4] = {};

  for (int kt = kstart; kt < kend; kt += 64) {
    // ---- K fragments (A-operand of S^T = K * Q) ----
    us8 kA[4][2];
#pragma unroll
    for (int f = 0; f < 4; ++f) {
      int krow = kt + (f & 1) * 32 + (lrow >> 2) * 8 + (f >> 1) * 4 + (lrow & 3);
      krow = min(krow, T_TOK - 1);
      const u16* kp = Kbase + (size_t)krow * D_HD + lg * 8;
      kA[f][0] = *(const us8*)(kp);
      kA[f][1] = *(const us8*)(kp + 32);
    }
    f32x4 s_[4];
#pragma unroll
    for (int f = 0; f < 4; ++f) {
      f32x4 z = {};
      z = mfma16(kA[f][0], qB0, z);
      s_[f] = mfma16(kA[f][1], qB1, z);
    }
    // ---- V fragments (issued early; latency hides under softmax) ----
    // NOTE: no clamp here! Slot j MUST correspond to key kt+ks*32+lg*8+j.
    // Overrun reads (< 104B past Vt's last row) land in the allocated Ctx
    // workspace region: finite bf16 garbage multiplied by masked P == 0.
    // (A min() clamp here misaligned slot<->key for valid keys near T and
    // cost absmax 1.57e-2 in round 3.)
    us8 vA[4][2];
#pragma unroll
    for (int nf = 0; nf < 4; ++nf) {
      const u16* vp = Vbase + (size_t)(nf * 16) * T_TOK;
#pragma unroll
      for (int ks = 0; ks < 2; ++ks) {
        int kc = kt + ks * 32 + lg * 8;
        vA[nf][ks] = *(const us8*)(vp + kc);
      }
    }
    // ---- masked online softmax (log2 domain), lane owns q=lrow ----
    float mx = -1e30f;
#pragma unroll
    for (int f = 0; f < 4; ++f) {
      int kb0 = kt + (f & 1) * 32 + lg * 8 + (f >> 1) * 4;
#pragma unroll
      for (int r = 0; r < 4; ++r) {
        int key = kb0 + r;
        float sv = (key >= kb && key < ke) ? s_[f][r] * scale2 : -1e30f;
        s_[f][r] = sv;
        mx = fmaxf(mx, sv);
      }
    }
    mx = fmaxf(mx, __shfl_xor(mx, 16));
    mx = fmaxf(mx, __shfl_xor(mx, 32));
    float mn = fmaxf(mrun, mx);
    float scf = exp2f(mrun - mn);
    mrun = mn;
    float ts = 0.f;
#pragma unroll
    for (int f = 0; f < 4; ++f)
#pragma unroll
      for (int r = 0; r < 4; ++r) {
        float p = exp2f(s_[f][r] - mn);
        s_[f][r] = p;
        ts += p;
      }
    lrun = lrun * scf + ts;   // per-lane partial sum; reduced once at end
#pragma unroll
    for (int nf = 0; nf < 4; ++nf)
#pragma unroll
      for (int r = 0; r < 4; ++r) accO[nf][r] *= scf;
    // ---- pack P to bf16 (pairs land exactly as PV B-frag words) ----
    u32 pw[8];
#pragma unroll
    for (int f = 0; f < 4; ++f)
#pragma unroll
      for (int pp = 0; pp < 2; ++pp)
        asm("v_cvt_pk_bf16_f32 %0, %1, %2"
            : "=v"(pw[f * 2 + pp])
            : "v"(s_[f][2 * pp]), "v"(s_[f][2 * pp + 1]));
    us8 pB0 = __builtin_bit_cast(us8, (u32x4){pw[0], pw[1], pw[4], pw[5]});
    us8 pB1 = __builtin_bit_cast(us8, (u32x4){pw[2], pw[3], pw[6], pw[7]});
    // ---- O^T += V^T * P^T ----
#pragma unroll
    for (int nf = 0; nf < 4; ++nf) {
      accO[nf] = mfma16(vA[nf][0], pB0, accO[nf]);
      accO[nf] = mfma16(vA[nf][1], pB1, accO[nf]);
    }
  }

  lrun += __shfl_xor(lrun, 16);
  lrun += __shfl_xor(lrun, 32);
  float inv = 1.f / lrun;
  u16* op = Ctx + (size_t)q * E_DIM + h * D_HD + lg * 4;
#pragma unroll
  for (int nf = 0; nf < 4; ++nf) {
    us4 o;
#pragma unroll
    for (int r = 0; r < 4; ++r) o[r] = f2bf(accO[nf][r] * inv);
    *(us4*)(op + nf * 16) = o;
  }
}

// ---------------------------------------------------------------------------
extern "C" void kernel_launch(void* const* d_in, const int* in_sizes, int n_in,
                              void* d_out, int out_size, void* d_ws, size_t ws_size,
                              hipStream_t stream) {
  const float* hs = (const float*)d_in[0];
  const int*   cu = (const int*)d_in[1];
  const float* Wq = (const float*)d_in[2];
  const float* bq = (const float*)d_in[3];
  const float* Wk = (const float*)d_in[4];
  const float* bk = (const float*)d_in[5];
  const float* Wv = (const float*)d_in[6];
  const float* bv = (const float*)d_in[7];
  const float* Wo = (const float*)d_in[8];
  const float* bo = (const float*)d_in[9];
  float* out = (float*)d_out;

  char* ws = (char*)d_ws;
  u16* Xb   = (u16*)(ws);
  u16* Wqkv = (u16*)(ws + 8ll * 1024 * 1024);
  u16* Wob  = (u16*)(ws + 14ll * 1024 * 1024);
  u16* Qh   = (u16*)(ws + 16ll * 1024 * 1024);  // [H][T][D]
  u16* Kh   = (u16*)(ws + 24ll * 1024 * 1024);  // [H][T][D]
  u16* Vt   = (u16*)(ws + 32ll * 1024 * 1024);  // [H*D][T]
  u16* Ctx  = (u16*)(ws + 40ll * 1024 * 1024);  // [T][E]

  cvt_all<<<8192, 256, 0, stream>>>(hs, Wq, Wk, Wv, Wo, Xb, Wqkv, Wob);
  gemm_bt<0><<<dim3(32 * 24), 256, 0, stream>>>(Xb, Wqkv, T_TOK, 3 * E_DIM, E_DIM,
                                                bq, bk, bv, Qh, Kh, Vt, nullptr);
  attn_varlen2<<<dim3(T_TOK / 64, H_N), 256, 0, stream>>>(Qh, Kh, Vt, cu, Ctx);
  gemm_bt<1><<<dim3(32 * 8), 256, 0, stream>>>(Ctx, Wob, T_TOK, E_DIM, E_DIM,
                                               bo, nullptr, nullptr,
                                               nullptr, nullptr, nullptr, out);
}

// Round 7
// 195.614 us; speedup vs baseline: 1.3313x; 1.3313x over previous
//
#include <hip/hip_runtime.h>
#include <stdint.h>

#define T_TOK 4096
#define E_DIM 1024
#define H_N   16
#define D_HD  64
#define NSEG  8

typedef unsigned short u16;
typedef uint32_t       u32;
typedef __bf16          bf16x8 __attribute__((ext_vector_type(8)));
typedef float           f32x4  __attribute__((ext_vector_type(4)));
typedef unsigned short  us8    __attribute__((ext_vector_type(8)));
typedef unsigned short  us4    __attribute__((ext_vector_type(4)));
typedef uint32_t        u32x4  __attribute__((ext_vector_type(4)));

__device__ __forceinline__ u16 f2bf(float f) {
  uint32_t u = __builtin_bit_cast(uint32_t, f);
  u += 0x7FFFu + ((u >> 16) & 1u);
  return (u16)(u >> 16);
}

__device__ __forceinline__ f32x4 mfma16(us8 a, us8 b, f32x4 c) {
  return __builtin_amdgcn_mfma_f32_16x16x32_bf16(
      __builtin_bit_cast(bf16x8, a), __builtin_bit_cast(bf16x8, b), c, 0, 0, 0);
}

__device__ __forceinline__ void async_load16(const void* g, void* l) {
  __builtin_amdgcn_global_load_lds(
      (const __attribute__((address_space(1))) void*)g,
      (__attribute__((address_space(3))) void*)l, 16, 0, 0);
}

// ---------------- fp32 -> bf16 conversion (hidden, Wqkv fused, Wo) ----------
__global__ __launch_bounds__(256) void cvt_all(
    const float* __restrict__ hs, const float* __restrict__ wq,
    const float* __restrict__ wk, const float* __restrict__ wv,
    const float* __restrict__ wo,
    u16* __restrict__ xb, u16* __restrict__ wqkv, u16* __restrict__ wob) {
  const int NH = T_TOK * E_DIM / 4;   // 1048576 float4s
  const int NW = E_DIM * E_DIM / 4;   // 262144 float4s
  int i = blockIdx.x * 256 + threadIdx.x;
  const float4* src; u16* dst; size_t off;
  if (i < NH)            { src = (const float4*)hs; dst = xb;   off = i; }
  else if (i < NH+NW)    { src = (const float4*)wq; dst = wqkv; off = i - NH;          src += off; off += 0;      goto L; }
  else if (i < NH+2*NW)  { src = (const float4*)wk; dst = wqkv; off = i - NH - NW;     src += off; off += NW;     goto L; }
  else if (i < NH+3*NW)  { src = (const float4*)wv; dst = wqkv; off = i - NH - 2*NW;   src += off; off += 2*NW;   goto L; }
  else                   { src = (const float4*)wo; dst = wob;  off = i - NH - 3*NW;   src += off;                goto L; }
  src += off;
L:
  float4 v = *src;
  us4 o;
  o[0] = f2bf(v.x); o[1] = f2bf(v.y); o[2] = f2bf(v.z); o[3] = f2bf(v.w);
  *(us4*)(dst + off * 4) = o;
}

// ---------------- bf16 GEMM: C[M,N] = A[M,K] * B[N,K]^T + bias --------------
// MODE 0: N=3072 -> Q,K in [H][T][D] bf16; V transposed [H*D][T] bf16
// MODE 1: fp32 out + bias0
template <int MODE>
__global__ __launch_bounds__(256, 2) void gemm_bt(
    const u16* __restrict__ A, const u16* __restrict__ B,
    int M, int N, int K,
    const float* __restrict__ bias0, const float* __restrict__ bias1,
    const float* __restrict__ bias2,
    u16* __restrict__ out_q, u16* __restrict__ out_k, u16* __restrict__ out_v,
    float* __restrict__ out_f) {
  __shared__ u16 As[2][128 * 32];
  __shared__ u16 Bs[2][128 * 32];

  const int nbn = N / 128;
  int bm = blockIdx.x / nbn, bn = blockIdx.x % nbn;
  int m0 = bm * 128, n0 = bn * 128;
  int tid = threadIdx.x, lane = tid & 63, wave = tid >> 6;
  int wr = wave >> 1, wc = wave & 1;

  f32x4 acc[4][4] = {};

  auto stage = [&](int bufi, int k0) {
#pragma unroll
    for (int r = 0; r < 2; ++r) {
      int chunk = r * 4 + wave;                 // 1KB chunk, wave-uniform
      int elem = chunk * 512 + lane * 8;        // elems into 128x32 tile
      int row = elem >> 5, kc = elem & 31;
      async_load16(A + (size_t)(m0 + row) * K + k0 + kc, (char*)As[bufi] + chunk * 1024);
      async_load16(B + (size_t)(n0 + row) * K + k0 + kc, (char*)Bs[bufi] + chunk * 1024);
    }
  };

  stage(0, 0);
  __syncthreads();
  int NT = K / 32;
  int lrow = lane & 15, lk = (lane >> 4) * 8;
  for (int t = 0; t < NT; ++t) {
    int buf = t & 1;
    if (t + 1 < NT) stage(buf ^ 1, (t + 1) * 32);
    us8 a[4], b[4];
#pragma unroll
    for (int i = 0; i < 4; ++i) {
      a[i] = *(const us8*)&As[buf][(wr * 64 + i * 16 + lrow) * 32 + lk];
      b[i] = *(const us8*)&Bs[buf][(wc * 64 + i * 16 + lrow) * 32 + lk];
    }
#pragma unroll
    for (int i = 0; i < 4; ++i)
#pragma unroll
      for (int j = 0; j < 4; ++j)
        acc[i][j] = mfma16(a[i], b[j], acc[i][j]);
    __syncthreads();
  }

  int lg = lane >> 4;
#pragma unroll
  for (int i = 0; i < 4; ++i) {
#pragma unroll
    for (int j = 0; j < 4; ++j) {
      int col = n0 + wc * 64 + j * 16 + lrow;
      int row0 = m0 + wr * 64 + i * 16 + lg * 4;
      if (MODE == 0) {
        if (col < 1024) {
          int hh = col >> 6, dd = col & 63;
          float bb = bias0[col];
          u16* dst = out_q + (size_t)hh * (T_TOK * D_HD) + dd;
#pragma unroll
          for (int r = 0; r < 4; ++r)
            dst[(size_t)(row0 + r) * D_HD] = f2bf(acc[i][j][r] + bb);
        } else if (col < 2048) {
          int c = col - 1024;
          int hh = c >> 6, dd = c & 63;
          float bb = bias1[c];
          u16* dst = out_k + (size_t)hh * (T_TOK * D_HD) + dd;
#pragma unroll
          for (int r = 0; r < 4; ++r)
            dst[(size_t)(row0 + r) * D_HD] = f2bf(acc[i][j][r] + bb);
        } else {
          int vc = col - 2048;                 // = h*64 + d
          float bb = bias2[vc];
          us4 o;
#pragma unroll
          for (int r = 0; r < 4; ++r) o[r] = f2bf(acc[i][j][r] + bb);
          *(us4*)&out_v[(size_t)vc * T_TOK + row0] = o;
        }
      } else {
        float bb = bias0[col];
#pragma unroll
        for (int r = 0; r < 4; ++r)
          out_f[(size_t)(row0 + r) * 1024 + col] = acc[i][j][r] + bb;
      }
    }
  }
}

// ---------------- varlen flash attention v3: LDS-staged K/V, reg softmax ----
// 1-D grid 1024 blocks (XCD-swizzled); block 256 = 4 waves; wave = 16 q-rows.
// K tile [key][d] and V^T tile [d][key] staged once per block via
// global_load_lds, double-buffered. LDS slot swizzle: phys_slot =
// log_slot ^ g(row), g(x) = (x&3)|(((x>>3)&1)<<2), applied by permuting the
// DMA *source* within each 128-B row (dest must stay linear) and XORing at
// read time -> even 8 lanes/slot on all ds_read_b128 patterns.
__global__ __launch_bounds__(256, 4) void attn_varlen3(
    const u16* __restrict__ Qh, const u16* __restrict__ Kh,
    const u16* __restrict__ Vt, const int* __restrict__ cu,
    u16* __restrict__ Ctx) {
  __shared__ u16 Ks[2][64 * 64];
  __shared__ u16 Vs[2][64 * 64];

  int orig = blockIdx.x;
  int swz = (orig & 7) * 128 + (orig >> 3);   // XCD-contiguous: 2 heads/XCD
  int qt = swz & 63, h = swz >> 6;
  int tid = threadIdx.x, lane = tid & 63, wave = tid >> 6;
  int lrow = lane & 15, lg = lane >> 4;
  int q0b = qt * 64;
  int q = q0b + wave * 16 + lrow;

  int cuv[NSEG + 1];
#pragma unroll
  for (int i = 0; i <= NSEG; ++i) cuv[i] = cu[i];

  int s = 0, sl = 0, sh = 0;
#pragma unroll
  for (int i = 1; i < NSEG; ++i) {
    s  += (q >= cuv[i]);
    sl += (q0b >= cuv[i]);
    sh += (q0b + 63 >= cuv[i]);
  }
  int kb = cuv[s], ke = cuv[s + 1];       // this lane's q segment
  int kt0 = cuv[sl] & ~7;                 // block-uniform, 16B-aligned DMA
  int kend = cuv[sh + 1];
  int NT = (kend - kt0 + 63) >> 6;

  const u16* qp = Qh + ((size_t)h * T_TOK + q) * D_HD + lg * 8;
  us8 qB0 = *(const us8*)(qp);
  us8 qB1 = *(const us8*)(qp + 32);

  const u16* Kbase = Kh + (size_t)h * (T_TOK * D_HD);
  const u16* Vbase = Vt + (size_t)h * (D_HD * T_TOK);

  // DMA source geometry: chunk c covers rows c*8..c*8+7; lane handles
  // row = c*8 + lane/8, phys slot = lane&7 -> source d/key group =
  // (lane&7) ^ g(row). Wave w owns chunks {2w, 2w+1} of both K and V.
  int c0 = wave * 2, c1 = wave * 2 + 1;
  int row0_ = c0 * 8 + (lane >> 3), row1_ = c1 * 8 + (lane >> 3);
  int g0 = (row0_ & 3) | (((row0_ >> 3) & 1) << 2);
  int g1 = (row1_ & 3) | (((row1_ >> 3) & 1) << 2);
  int ss0 = (lane & 7) ^ g0, ss1 = (lane & 7) ^ g1;

  auto stage = [&](int bufi, int ktn) {
    async_load16(Kbase + (size_t)(ktn + row0_) * D_HD + ss0 * 8,
                 (char*)Ks[bufi] + c0 * 1024);
    async_load16(Kbase + (size_t)(ktn + row1_) * D_HD + ss1 * 8,
                 (char*)Ks[bufi] + c1 * 1024);
    async_load16(Vbase + (size_t)row0_ * T_TOK + ktn + ss0 * 8,
                 (char*)Vs[bufi] + c0 * 1024);
    async_load16(Vbase + (size_t)row1_ * T_TOK + ktn + ss1 * 8,
                 (char*)Vs[bufi] + c1 * 1024);
  };

  const float scale2 = 0.125f * 1.44269504f;  // scale * log2(e)
  float mrun = -1e30f, lrun = 0.f;
  f32x4 accO[4] = {};

  stage(0, kt0);
  __syncthreads();   // drains vmcnt(0) before barrier (compiler-inserted)

  for (int t = 0; t < NT; ++t) {
    int ktn = kt0 + t * 64;
    int buf = t & 1;
    if (t + 1 < NT) stage(buf ^ 1, ktn + 64);   // prefetch next tile

    // ---- K fragments from LDS (A-operand of S^T = K * Q) ----
    us8 kA[4][2];
#pragma unroll
    for (int f = 0; f < 4; ++f) {
      int krl = (f & 1) * 32 + (lrow >> 2) * 8 + (f >> 1) * 4 + (lrow & 3);
      int gk = (krl & 3) | (((krl >> 3) & 1) << 2);
      kA[f][0] = *(const us8*)((char*)Ks[buf] + krl * 128 + (lg ^ gk) * 16);
      kA[f][1] = *(const us8*)((char*)Ks[buf] + krl * 128 + ((lg | 4) ^ gk) * 16);
    }
    f32x4 s_[4];
#pragma unroll
    for (int f = 0; f < 4; ++f) {
      f32x4 z = {};
      z = mfma16(kA[f][0], qB0, z);
      s_[f] = mfma16(kA[f][1], qB1, z);
    }

    // ---- V fragments from LDS ----
    us8 vA[4][2];
#pragma unroll
    for (int nf = 0; nf < 4; ++nf) {
      int d_l = nf * 16 + lrow;
      int gv = (d_l & 3) | (((d_l >> 3) & 1) << 2);
#pragma unroll
      for (int ks = 0; ks < 2; ++ks)
        vA[nf][ks] = *(const us8*)((char*)Vs[buf] + d_l * 128 +
                                   (((ks << 2) | lg) ^ gv) * 16);
    }

    // ---- masked online softmax (log2 domain), lane owns q row ----
    float mx = -1e30f;
#pragma unroll
    for (int f = 0; f < 4; ++f) {
      int kb0 = ktn + (f & 1) * 32 + lg * 8 + (f >> 1) * 4;
#pragma unroll
      for (int r = 0; r < 4; ++r) {
        int key = kb0 + r;
        float sv = (key >= kb && key < ke) ? s_[f][r] * scale2 : -1e30f;
        s_[f][r] = sv;
        mx = fmaxf(mx, sv);
      }
    }
    mx = fmaxf(mx, __shfl_xor(mx, 16));
    mx = fmaxf(mx, __shfl_xor(mx, 32));
    float mn = fmaxf(mrun, mx);
    float scf = exp2f(mrun - mn);
    mrun = mn;
    float ts = 0.f;
#pragma unroll
    for (int f = 0; f < 4; ++f)
#pragma unroll
      for (int r = 0; r < 4; ++r) {
        float p = exp2f(s_[f][r] - mn);
        s_[f][r] = p;
        ts += p;
      }
    lrun = lrun * scf + ts;
#pragma unroll
    for (int nf = 0; nf < 4; ++nf)
#pragma unroll
      for (int r = 0; r < 4; ++r) accO[nf][r] *= scf;

    // ---- pack P to bf16 (pairs land exactly as PV B-frag words) ----
    u32 pw[8];
#pragma unroll
    for (int f = 0; f < 4; ++f)
#pragma unroll
      for (int pp = 0; pp < 2; ++pp)
        asm("v_cvt_pk_bf16_f32 %0, %1, %2"
            : "=v"(pw[f * 2 + pp])
            : "v"(s_[f][2 * pp]), "v"(s_[f][2 * pp + 1]));
    us8 pB0 = __builtin_bit_cast(us8, (u32x4){pw[0], pw[1], pw[4], pw[5]});
    us8 pB1 = __builtin_bit_cast(us8, (u32x4){pw[2], pw[3], pw[6], pw[7]});

    // ---- O^T += V^T * P^T ----
#pragma unroll
    for (int nf = 0; nf < 4; ++nf) {
      accO[nf] = mfma16(vA[nf][0], pB0, accO[nf]);
      accO[nf] = mfma16(vA[nf][1], pB1, accO[nf]);
    }

    __syncthreads();  // drains my prefetch DMAs (hidden under compute) + bar
  }

  lrun += __shfl_xor(lrun, 16);
  lrun += __shfl_xor(lrun, 32);
  float inv = 1.f / lrun;
  u16* op = Ctx + (size_t)q * E_DIM + h * D_HD + lg * 4;
#pragma unroll
  for (int nf = 0; nf < 4; ++nf) {
    us4 o;
#pragma unroll
    for (int r = 0; r < 4; ++r) o[r] = f2bf(accO[nf][r] * inv);
    *(us4*)(op + nf * 16) = o;
  }
}

// ---------------------------------------------------------------------------
extern "C" void kernel_launch(void* const* d_in, const int* in_sizes, int n_in,
                              void* d_out, int out_size, void* d_ws, size_t ws_size,
                              hipStream_t stream) {
  const float* hs = (const float*)d_in[0];
  const int*   cu = (const int*)d_in[1];
  const float* Wq = (const float*)d_in[2];
  const float* bq = (const float*)d_in[3];
  const float* Wk = (const float*)d_in[4];
  const float* bk = (const float*)d_in[5];
  const float* Wv = (const float*)d_in[6];
  const float* bv = (const float*)d_in[7];
  const float* Wo = (const float*)d_in[8];
  const float* bo = (const float*)d_in[9];
  float* out = (float*)d_out;

  char* ws = (char*)d_ws;
  u16* Xb   = (u16*)(ws);
  u16* Wqkv = (u16*)(ws + 8ll * 1024 * 1024);
  u16* Wob  = (u16*)(ws + 14ll * 1024 * 1024);
  u16* Qh   = (u16*)(ws + 16ll * 1024 * 1024);  // [H][T][D]
  u16* Kh   = (u16*)(ws + 24ll * 1024 * 1024);  // [H][T][D]
  u16* Vt   = (u16*)(ws + 32ll * 1024 * 1024);  // [H*D][T]
  u16* Ctx  = (u16*)(ws + 40ll * 1024 * 1024);  // [T][E]

  cvt_all<<<8192, 256, 0, stream>>>(hs, Wq, Wk, Wv, Wo, Xb, Wqkv, Wob);
  gemm_bt<0><<<dim3(32 * 24), 256, 0, stream>>>(Xb, Wqkv, T_TOK, 3 * E_DIM, E_DIM,
                                                bq, bk, bv, Qh, Kh, Vt, nullptr);
  attn_varlen3<<<dim3(64 * 16), 256, 0, stream>>>(Qh, Kh, Vt, cu, Ctx);
  gemm_bt<1><<<dim3(32 * 8), 256, 0, stream>>>(Ctx, Wob, T_TOK, E_DIM, E_DIM,
                                               bo, nullptr, nullptr,
                                               nullptr, nullptr, nullptr, out);
}